// Round 3
// baseline (286.446 us; speedup 1.0000x reference)
//
#include <hip/hip_runtime.h>
#include <math.h>

#define KNN 16
#define CH 64
#define HID 16
#define NEG_BIG (-3.402823466e+38f)

__device__ __forceinline__ float sigmoidf_(float x) {
    return 1.0f / (1.0f + __expf(-x));
}

// fold-reduce across a 16-lane group: on entry v[h] = this lane's partial for
// output h; on exit, return value on lane `sub` is the full sum for h == sub.
__device__ __forceinline__ float fold16(float v[HID], int sub) {
    #pragma unroll
    for (int m = 8; m >= 1; m >>= 1) {
        bool hi = (sub & m) != 0;
        #pragma unroll
        for (int i = 0; i < m; ++i) {
            float s    = hi ? v[i] : v[i + m];
            float keep = hi ? v[i + m] : v[i];
            v[i] = keep + __shfl_xor(s, m);
        }
    }
    return v[0];
}

// Phase A: channel attention. 16 lanes per point (4 points/wave).
// Gathers staged via global_load_lds (async, width=16): in-flight data lives
// in LDS, so VGPR pressure no longer caps memory-level parallelism (R2: the
// allocator gave 40 VGPRs and serialized the gather ~6 deep).
// LDS: 32KB stage + 8KB weights = 40KB -> 4 blocks/CU, 4 waves/SIMD.
__global__ __launch_bounds__(256, 4) void kA(const float4* __restrict__ xv,
        const float* __restrict__ W1, const float* __restrict__ b1,
        const float* __restrict__ W2, const float* __restrict__ b2,
        const int4* __restrict__ idxv,
        float4* __restrict__ outse, float2* __restrict__ rowstat, int n) {
    __shared__ float4 w1q[256];          // w1q[h*16+s] = W1[(4s+i)*HID+h], i=0..3
    __shared__ float4 w2q[256];          // float4 copy of W2 (16x64 row-major)
    __shared__ float4 stage[4][8][64];   // [wave][slot][lane] wave-private staging

    int t = threadIdx.x;
    {
        int h = t >> 4, s = t & 15;
        float4 a;
        a.x = W1[(4 * s + 0) * HID + h];
        a.y = W1[(4 * s + 1) * HID + h];
        a.z = W1[(4 * s + 2) * HID + h];
        a.w = W1[(4 * s + 3) * HID + h];
        w1q[t] = a;
        w2q[t] = ((const float4*)W2)[t];
    }
    __syncthreads();

    int p = blockIdx.x * 16 + (t >> 4);
    int sub = t & 15;
    int w = t >> 6;
    int lane = t & 63;
    if (p >= n) return;   // grid is exact for n=100000; guard is for safety

    // all 16 neighbor indices (same 32B per 16-lane group -> L1 broadcast)
    int4 ja0 = idxv[p * 4 + 0];
    int4 jb0 = idxv[p * 4 + 1];
    int4 ja1 = idxv[p * 4 + 2];
    int4 jb1 = idxv[p * 4 + 3];

    // async gather: lane sub of each group fetches float4 #sub of row j.
    // HW scatters lane i of the wave to (uniform LDS base) + i*16 -> stage[w][k][lane].
    auto issue = [&](int j, int k) {
        __builtin_amdgcn_global_load_lds(
            (const __attribute__((address_space(1))) void*)(xv + ((size_t)j * 16 + sub)),
            (__attribute__((address_space(3))) void*)(&stage[w][k][0]),
            16, 0, 0);
    };

    // round 0: slots 0..7 all in flight
    issue(ja0.x, 0); issue(ja0.y, 1); issue(ja0.z, 2); issue(ja0.w, 3);
    issue(jb0.x, 4); issue(jb0.y, 5); issue(jb0.z, 6); issue(jb0.w, 7);
    float4 own = xv[p * 16 + sub];       // overlaps with staging
    float bb = b1[sub];
    float4 bq = ((const float4*)b2)[sub];

    __builtin_amdgcn_s_waitcnt(0x0F70);  // vmcnt(0); don't wait exp/lgkm

    float4 sum, mx;
    {
        float4 v = stage[w][0][lane];
        sum = v; mx = v;
    }
    #pragma unroll
    for (int k = 1; k < 8; ++k) {
        float4 v = stage[w][k][lane];
        sum.x += v.x; sum.y += v.y; sum.z += v.z; sum.w += v.w;
        mx.x = fmaxf(mx.x, v.x); mx.y = fmaxf(mx.y, v.y);
        mx.z = fmaxf(mx.z, v.z); mx.w = fmaxf(mx.w, v.w);
    }

    // round 1: reuse slots (WAR safe: ds_reads above are issued before these
    // writes can land; program order preserved by LDS aliasing)
    issue(ja1.x, 0); issue(ja1.y, 1); issue(ja1.z, 2); issue(ja1.w, 3);
    issue(jb1.x, 4); issue(jb1.y, 5); issue(jb1.z, 6); issue(jb1.w, 7);
    __builtin_amdgcn_s_waitcnt(0x0F70);

    #pragma unroll
    for (int k = 0; k < 8; ++k) {
        float4 v = stage[w][k][lane];
        sum.x += v.x; sum.y += v.y; sum.z += v.z; sum.w += v.w;
        mx.x = fmaxf(mx.x, v.x); mx.y = fmaxf(mx.y, v.y);
        mx.z = fmaxf(mx.z, v.z); mx.w = fmaxf(mx.w, v.w);
    }

    const float inv_k = 1.0f / KNN;
    float4 mean = {sum.x * inv_k, sum.y * inv_k, sum.z * inv_k, sum.w * inv_k};

    // layer 1, mean path then max path
    float Hm, Hx;
    {
        float pm[HID];
        #pragma unroll
        for (int h = 0; h < HID; ++h) {
            float4 wv = w1q[h * 16 + sub];
            pm[h] = mean.x * wv.x + mean.y * wv.y + mean.z * wv.z + mean.w * wv.w;
        }
        Hm = fold16(pm, sub);
    }
    {
        float px[HID];
        #pragma unroll
        for (int h = 0; h < HID; ++h) {
            float4 wv = w1q[h * 16 + sub];
            px[h] = mx.x * wv.x + mx.y * wv.y + mx.z * wv.z + mx.w * wv.w;
        }
        Hx = fold16(px, sub);
    }
    float H = fmaxf(Hm + bb, 0.0f) + fmaxf(Hx + bb, 0.0f);

    // layer 2: out4[c] = sum_h H[h] * W2[h][c]
    float4 acc = {0.f, 0.f, 0.f, 0.f};
    #pragma unroll
    for (int h = 0; h < HID; ++h) {
        float Hh = __shfl(H, h, 16);
        float4 wv = w2q[h * 16 + sub];
        acc.x += Hh * wv.x; acc.y += Hh * wv.y; acc.z += Hh * wv.z; acc.w += Hh * wv.w;
    }
    float4 o;
    o.x = own.x * sigmoidf_(acc.x + 2.0f * bq.x);
    o.y = own.y * sigmoidf_(acc.y + 2.0f * bq.y);
    o.z = own.z * sigmoidf_(acc.z + 2.0f * bq.z);
    o.w = own.w * sigmoidf_(acc.w + 2.0f * bq.w);
    outse[p * 16 + sub] = o;

    // per-row stats so phase B gathers 8B/neighbor instead of 256B
    float sm = o.x + o.y + o.z + o.w;
    float sx = fmaxf(fmaxf(o.x, o.y), fmaxf(o.z, o.w));
    #pragma unroll
    for (int m = 8; m >= 1; m >>= 1) {
        sm += __shfl_xor(sm, m);
        sx = fmaxf(sx, __shfl_xor(sx, m));
    }
    if (sub == 0) rowstat[p] = make_float2(sm * (1.0f / 64.0f), sx);
}

// Phase B: z[n] = (mean_k rowmean, max_k rowmax) over knn neighbors
__global__ __launch_bounds__(256) void kB(const int4* __restrict__ idxv,
        const float2* __restrict__ rowstat, float2* __restrict__ z, int n) {
    int i = blockIdx.x * 256 + threadIdx.x;
    if (i >= n) return;
    float zm = 0.0f, zx = NEG_BIG;
    #pragma unroll
    for (int q = 0; q < 4; ++q) {
        int4 jj = idxv[i * 4 + q];
        float2 s0 = rowstat[jj.x];
        float2 s1 = rowstat[jj.y];
        float2 s2 = rowstat[jj.z];
        float2 s3 = rowstat[jj.w];
        zm += s0.x + s1.x + s2.x + s3.x;
        zx = fmaxf(zx, fmaxf(fmaxf(s0.y, s1.y), fmaxf(s2.y, s3.y)));
    }
    z[i] = make_float2(zm * (1.0f / 16.0f), zx);
}

// Phase C (fused conv + scale): sig per point via LDS, then out = outse * sig
__global__ __launch_bounds__(256) void kC(const int* __restrict__ conv_idx,
        const float* __restrict__ conv_w, const float2* __restrict__ z,
        const float4* __restrict__ outse, float4* __restrict__ out, int n) {
    __shared__ float cw[54];
    __shared__ float sgate[256];
    if (threadIdx.x < 54) cw[threadIdx.x] = conv_w[threadIdx.x];
    __syncthreads();
    int base = blockIdx.x * 256;
    int i = base + threadIdx.x;
    if (i < n) {
        float acc = 0.0f;
        #pragma unroll
        for (int k = 0; k < 27; ++k) {
            int j = conv_idx[i * 27 + k];      // branchless: clamp + mask
            int jc = j >= 0 ? j : 0;
            float msk = j >= 0 ? 1.0f : 0.0f;
            float2 zz = z[jc];
            acc += msk * (zz.x * cw[2 * k] + zz.y * cw[2 * k + 1]);
        }
        sgate[threadIdx.x] = sigmoidf_(acc);
    }
    __syncthreads();
    int npts = n - base; if (npts > 256) npts = 256;
    int tot = npts * 16;                       // float4s this block owns
    for (int q = threadIdx.x; q < tot; q += 256) {
        float s = sgate[q >> 4];
        float4 v = outse[(size_t)base * 16 + q];
        float4 r = make_float4(v.x * s, v.y * s, v.z * s, v.w * s);
        out[(size_t)base * 16 + q] = r;
    }
}

extern "C" void kernel_launch(void* const* d_in, const int* in_sizes, int n_in,
                              void* d_out, int out_size, void* d_ws, size_t ws_size,
                              hipStream_t stream) {
    const float* x_F    = (const float*)d_in[0];
    const float* W1     = (const float*)d_in[1];
    const float* b1     = (const float*)d_in[2];
    const float* W2     = (const float*)d_in[3];
    const float* b2     = (const float*)d_in[4];
    const float* conv_w = (const float*)d_in[5];
    const int*   idx    = (const int*)d_in[6];
    const int*   cidx   = (const int*)d_in[7];
    int n = in_sizes[0] / CH;   // 100000

    char* ws = (char*)d_ws;
    float*  outse   = (float*)ws;                                  // n*64 f32
    float2* rowstat = (float2*)(ws + (size_t)n * CH * 4);          // n float2
    float2* zz      = (float2*)(ws + (size_t)n * CH * 4 + (size_t)n * 8);

    int blkA = (n + 15) / 16;
    kA<<<blkA, 256, 0, stream>>>((const float4*)x_F, W1, b1, W2, b2,
                                 (const int4*)idx, (float4*)outse, rowstat, n);
    int blkP = (n + 255) / 256;
    kB<<<blkP, 256, 0, stream>>>((const int4*)idx, rowstat, zz, n);
    kC<<<blkP, 256, 0, stream>>>(cidx, conv_w, zz, (const float4*)outse,
                                 (float4*)d_out, n);
}

// Round 4
// 244.213 us; speedup vs baseline: 1.1729x; 1.1729x over previous
//
#include <hip/hip_runtime.h>
#include <math.h>

#define KNN 16
#define CH 64
#define HID 16
#define NEG_BIG (-3.402823466e+38f)

__device__ __forceinline__ float sigmoidf_(float x) {
    return 1.0f / (1.0f + __expf(-x));
}

// pack two fp32 into bf16x2 (RNE), a in low16, b in high16
__device__ __forceinline__ unsigned int pack_bf2(float a, float b) {
    unsigned int ua = __float_as_uint(a), ub = __float_as_uint(b);
    ua = (ua + 0x7FFFu + ((ua >> 16) & 1u)) >> 16;
    ub = (ub + 0x7FFFu + ((ub >> 16) & 1u)) & 0xFFFF0000u;
    return ua | ub;
}

// unpack uint2 (4 bf16) -> float4, matching pack_bf2 layout
__device__ __forceinline__ float4 bf4_to_f4(uint2 b) {
    float4 r;
    r.x = __uint_as_float(b.x << 16);
    r.y = __uint_as_float(b.x & 0xFFFF0000u);
    r.z = __uint_as_float(b.y << 16);
    r.w = __uint_as_float(b.y & 0xFFFF0000u);
    return r;
}

// fold-reduce across a 16-lane group: on entry v[h] = this lane's partial for
// output h; on exit, return value on lane `sub` is the full sum for h == sub.
__device__ __forceinline__ float fold16(float v[HID], int sub) {
    #pragma unroll
    for (int m = 8; m >= 1; m >>= 1) {
        bool hi = (sub & m) != 0;
        #pragma unroll
        for (int i = 0; i < m; ++i) {
            float s    = hi ? v[i] : v[i + m];
            float keep = hi ? v[i + m] : v[i];
            v[i] = keep + __shfl_xor(s, m);
        }
    }
    return v[0];
}

// Pre-pass: bf16 copy of x_F. Halves gather bytes + cache footprint for kA.
__global__ __launch_bounds__(256) void kX(const float4* __restrict__ xv,
                                          uint2* __restrict__ xb, int n16) {
    int i = blockIdx.x * 256 + threadIdx.x;
    if (i >= n16) return;
    float4 v = xv[i];
    uint2 r;
    r.x = pack_bf2(v.x, v.y);
    r.y = pack_bf2(v.z, v.w);
    xb[i] = r;
}

// Phase A: channel attention. 16 lanes per point (4 points/wave), lane owns 4
// channels. Gathers hit the bf16 table (8B/lane, 128B/row, fully coalesced per
// group). VGPR gathers (R3's global_load_lds bypassed L1/L2 caching of the
// table and doubled fabric traffic — reverted). vbuf is 32 VGPRs so all 16
// loads can be in flight.
__global__ __launch_bounds__(256, 4) void kA(const float4* __restrict__ xv,
        const uint2* __restrict__ xb,
        const float* __restrict__ W1, const float* __restrict__ b1,
        const float* __restrict__ W2, const float* __restrict__ b2,
        const int* __restrict__ idx,
        float4* __restrict__ outse, float2* __restrict__ rowstat, int n) {
    __shared__ float4 w1q[256];   // w1q[h*16+s] = W1[(4s+i)*HID+h], i=0..3
    __shared__ float4 w2q[256];   // float4 copy of W2 (16x64 row-major)
    int t = threadIdx.x;
    {
        int h = t >> 4, s = t & 15;
        float4 a;
        a.x = W1[(4 * s + 0) * HID + h];
        a.y = W1[(4 * s + 1) * HID + h];
        a.z = W1[(4 * s + 2) * HID + h];
        a.w = W1[(4 * s + 3) * HID + h];
        w1q[t] = a;
        w2q[t] = ((const float4*)W2)[t];
    }
    __syncthreads();

    int p = blockIdx.x * 16 + (t >> 4);
    int sub = t & 15;
    if (p >= n) return;

    // 16 neighbor indices: 4 uniform int4 loads per group (L1 broadcast)
    const int4* ip = (const int4*)(idx + (size_t)p * KNN);
    int4 i0 = ip[0], i1 = ip[1], i2 = ip[2], i3 = ip[3];
    int jall[KNN] = {i0.x, i0.y, i0.z, i0.w, i1.x, i1.y, i1.z, i1.w,
                     i2.x, i2.y, i2.z, i2.w, i3.x, i3.y, i3.z, i3.w};

    // issue all 16 bf16 gathers back-to-back
    uint2 vbuf[KNN];
    #pragma unroll
    for (int k = 0; k < KNN; ++k) vbuf[k] = xb[(size_t)jall[k] * 16 + sub];
    float4 own = xv[(size_t)p * 16 + sub];   // fp32 own row, in flight too
    float bb = b1[sub];
    float4 bq = ((const float4*)b2)[sub];

    float4 sum, mx;
    {
        float4 v = bf4_to_f4(vbuf[0]);
        sum = v; mx = v;
    }
    #pragma unroll
    for (int k = 1; k < KNN; ++k) {
        float4 v = bf4_to_f4(vbuf[k]);
        sum.x += v.x; sum.y += v.y; sum.z += v.z; sum.w += v.w;
        mx.x = fmaxf(mx.x, v.x); mx.y = fmaxf(mx.y, v.y);
        mx.z = fmaxf(mx.z, v.z); mx.w = fmaxf(mx.w, v.w);
    }
    const float inv_k = 1.0f / KNN;
    float4 mean = {sum.x * inv_k, sum.y * inv_k, sum.z * inv_k, sum.w * inv_k};

    // layer 1, mean path then max path
    float Hm, Hx;
    {
        float pm[HID];
        #pragma unroll
        for (int h = 0; h < HID; ++h) {
            float4 wv = w1q[h * 16 + sub];
            pm[h] = mean.x * wv.x + mean.y * wv.y + mean.z * wv.z + mean.w * wv.w;
        }
        Hm = fold16(pm, sub);
    }
    {
        float px[HID];
        #pragma unroll
        for (int h = 0; h < HID; ++h) {
            float4 wv = w1q[h * 16 + sub];
            px[h] = mx.x * wv.x + mx.y * wv.y + mx.z * wv.z + mx.w * wv.w;
        }
        Hx = fold16(px, sub);
    }
    float H = fmaxf(Hm + bb, 0.0f) + fmaxf(Hx + bb, 0.0f);

    // layer 2: out4[c] = sum_h H[h] * W2[h][c]
    float4 acc = {0.f, 0.f, 0.f, 0.f};
    #pragma unroll
    for (int h = 0; h < HID; ++h) {
        float Hh = __shfl(H, h, 16);
        float4 wv = w2q[h * 16 + sub];
        acc.x += Hh * wv.x; acc.y += Hh * wv.y; acc.z += Hh * wv.z; acc.w += Hh * wv.w;
    }
    float4 o;
    o.x = own.x * sigmoidf_(acc.x + 2.0f * bq.x);
    o.y = own.y * sigmoidf_(acc.y + 2.0f * bq.y);
    o.z = own.z * sigmoidf_(acc.z + 2.0f * bq.z);
    o.w = own.w * sigmoidf_(acc.w + 2.0f * bq.w);
    outse[(size_t)p * 16 + sub] = o;

    // per-row stats so phase B gathers 8B/neighbor instead of 256B
    float sm = o.x + o.y + o.z + o.w;
    float sx = fmaxf(fmaxf(o.x, o.y), fmaxf(o.z, o.w));
    #pragma unroll
    for (int m = 8; m >= 1; m >>= 1) {
        sm += __shfl_xor(sm, m);
        sx = fmaxf(sx, __shfl_xor(sx, m));
    }
    if (sub == 0) rowstat[p] = make_float2(sm * (1.0f / 64.0f), sx);
}

// Phase B: z[n] = (mean_k rowmean, max_k rowmax). 2 lanes per point (8 gathers
// each) -> 2x wave concurrency on this latency-bound gather.
__global__ __launch_bounds__(256) void kB(const int4* __restrict__ idxv,
        const float2* __restrict__ rowstat, float2* __restrict__ z, int n) {
    int t = blockIdx.x * 256 + threadIdx.x;
    int i = t >> 1, half = t & 1;
    if (i >= n) return;
    int4 a = idxv[(size_t)i * 4 + half * 2];
    int4 b = idxv[(size_t)i * 4 + half * 2 + 1];
    float2 s0 = rowstat[a.x], s1 = rowstat[a.y], s2 = rowstat[a.z], s3 = rowstat[a.w];
    float2 s4 = rowstat[b.x], s5 = rowstat[b.y], s6 = rowstat[b.z], s7 = rowstat[b.w];
    float zm = (s0.x + s1.x) + (s2.x + s3.x) + ((s4.x + s5.x) + (s6.x + s7.x));
    float zx = fmaxf(fmaxf(fmaxf(s0.y, s1.y), fmaxf(s2.y, s3.y)),
                     fmaxf(fmaxf(s4.y, s5.y), fmaxf(s6.y, s7.y)));
    zm += __shfl_xor(zm, 1);
    zx = fmaxf(zx, __shfl_xor(zx, 1));
    if (half == 0) z[i] = make_float2(zm * (1.0f / 16.0f), zx);
}

// Phase C (fused conv + scale): sig per point via LDS, then out = outse * sig
__global__ __launch_bounds__(256) void kC(const int* __restrict__ conv_idx,
        const float* __restrict__ conv_w, const float2* __restrict__ z,
        const float4* __restrict__ outse, float4* __restrict__ out, int n) {
    __shared__ float cw[54];
    __shared__ float sgate[256];
    if (threadIdx.x < 54) cw[threadIdx.x] = conv_w[threadIdx.x];
    __syncthreads();
    int base = blockIdx.x * 256;
    int i = base + threadIdx.x;
    if (i < n) {
        float acc = 0.0f;
        #pragma unroll
        for (int k = 0; k < 27; ++k) {
            int j = conv_idx[(size_t)i * 27 + k];   // branchless clamp + mask
            int jc = j >= 0 ? j : 0;
            float msk = j >= 0 ? 1.0f : 0.0f;
            float2 zz = z[jc];
            acc += msk * (zz.x * cw[2 * k] + zz.y * cw[2 * k + 1]);
        }
        sgate[threadIdx.x] = sigmoidf_(acc);
    }
    __syncthreads();
    int npts = n - base; if (npts > 256) npts = 256;
    int tot = npts * 16;                            // float4s this block owns
    for (int q = threadIdx.x; q < tot; q += 256) {
        float s = sgate[q >> 4];
        float4 v = outse[(size_t)base * 16 + q];
        out[(size_t)base * 16 + q] = make_float4(v.x * s, v.y * s, v.z * s, v.w * s);
    }
}

extern "C" void kernel_launch(void* const* d_in, const int* in_sizes, int n_in,
                              void* d_out, int out_size, void* d_ws, size_t ws_size,
                              hipStream_t stream) {
    const float* x_F    = (const float*)d_in[0];
    const float* W1     = (const float*)d_in[1];
    const float* b1     = (const float*)d_in[2];
    const float* W2     = (const float*)d_in[3];
    const float* b2     = (const float*)d_in[4];
    const float* conv_w = (const float*)d_in[5];
    const int*   idx    = (const int*)d_in[6];
    const int*   cidx   = (const int*)d_in[7];
    int n = in_sizes[0] / CH;   // 100000

    char* ws = (char*)d_ws;
    size_t off = 0;
    uint2*  xb      = (uint2*)(ws + off);  off += (size_t)n * CH * 2;   // bf16 table, 12.8 MB
    float*  outse   = (float*)(ws + off);  off += (size_t)n * CH * 4;   // 25.6 MB
    float2* rowstat = (float2*)(ws + off); off += (size_t)n * 8;
    float2* zz      = (float2*)(ws + off); off += (size_t)n * 8;

    int n16 = n * 16;
    kX<<<(n16 + 255) / 256, 256, 0, stream>>>((const float4*)x_F, xb, n16);
    int blkA = (n + 15) / 16;
    kA<<<blkA, 256, 0, stream>>>((const float4*)x_F, xb, W1, b1, W2, b2, idx,
                                 (float4*)outse, rowstat, n);
    int blkB = (2 * n + 255) / 256;
    kB<<<blkB, 256, 0, stream>>>((const int4*)idx, rowstat, zz, n);
    int blkP = (n + 255) / 256;
    kC<<<blkP, 256, 0, stream>>>(cidx, conv_w, zz, (const float4*)outse,
                                 (float4*)d_out, n);
}

// Round 5
// 243.106 us; speedup vs baseline: 1.1783x; 1.0046x over previous
//
#include <hip/hip_runtime.h>
#include <math.h>

#define KNN 16
#define CH 64
#define HID 16
#define NEG_BIG (-3.402823466e+38f)

__device__ __forceinline__ float sigmoidf_(float x) {
    return 1.0f / (1.0f + __expf(-x));
}

// pack two fp32 into bf16x2 (RNE), a in low16, b in high16
__device__ __forceinline__ unsigned int pack_bf2(float a, float b) {
    unsigned int ua = __float_as_uint(a), ub = __float_as_uint(b);
    ua = (ua + 0x7FFFu + ((ua >> 16) & 1u)) >> 16;
    ub = (ub + 0x7FFFu + ((ub >> 16) & 1u)) & 0xFFFF0000u;
    return ua | ub;
}

// unpack uint2 (4 bf16) -> float4, matching pack_bf2 layout
__device__ __forceinline__ float4 bf4_to_f4(uint2 b) {
    float4 r;
    r.x = __uint_as_float(b.x << 16);
    r.y = __uint_as_float(b.x & 0xFFFF0000u);
    r.z = __uint_as_float(b.y << 16);
    r.w = __uint_as_float(b.y & 0xFFFF0000u);
    return r;
}

// fold-reduce across a 16-lane group: on entry v[h] = this lane's partial for
// output h; on exit, return value on lane `sub` is the full sum for h == sub.
__device__ __forceinline__ float fold16(float v[HID], int sub) {
    #pragma unroll
    for (int m = 8; m >= 1; m >>= 1) {
        bool hi = (sub & m) != 0;
        #pragma unroll
        for (int i = 0; i < m; ++i) {
            float s    = hi ? v[i] : v[i + m];
            float keep = hi ? v[i + m] : v[i];
            v[i] = keep + __shfl_xor(s, m);
        }
    }
    return v[0];
}

// Pre-pass: bf16 copy of x_F. Halves gather lines + cache footprint for kA.
__global__ __launch_bounds__(256) void kX(const float4* __restrict__ xv,
                                          uint2* __restrict__ xb, int n16) {
    int i = blockIdx.x * 256 + threadIdx.x;
    if (i >= n16) return;
    float4 v = xv[i];
    uint2 r;
    r.x = pack_bf2(v.x, v.y);
    r.y = pack_bf2(v.z, v.w);
    xb[i] = r;
}

// Phase A: channel attention. 16 lanes per point (4 points/wave), lane owns 4
// channels. EXACT R2 skeleton (0 spills / 0 LDS conflicts at 40 VGPR); only
// change: gather the bf16 table (uint2, 8B/lane -> 128B/row, half the
// L2-miss lines of fp32). R4's int4-idx + 16-deep uint2 variant spilled
// (WRITE +12MB) and picked up 6.4M LDS conflicts — reverted to __shfl
// index broadcast.
__global__ __launch_bounds__(256, 4) void kA(const float4* __restrict__ xv,
        const uint2* __restrict__ xb,
        const float* __restrict__ W1, const float* __restrict__ b1,
        const float* __restrict__ W2, const float* __restrict__ b2,
        const int* __restrict__ idx,
        float4* __restrict__ outse, float2* __restrict__ rowstat, int n) {
    __shared__ float4 w1q[256];   // w1q[h*16+s] = W1[(4s+i)*HID+h], i=0..3
    __shared__ float4 w2q[256];   // float4 copy of W2 (16x64 row-major)
    int t = threadIdx.x;
    {
        int h = t >> 4, s = t & 15;
        float4 a;
        a.x = W1[(4 * s + 0) * HID + h];
        a.y = W1[(4 * s + 1) * HID + h];
        a.z = W1[(4 * s + 2) * HID + h];
        a.w = W1[(4 * s + 3) * HID + h];
        w1q[t] = a;
        w2q[t] = ((const float4*)W2)[t];
    }
    __syncthreads();

    int p = blockIdx.x * 16 + (t >> 4);
    int sub = t & 15;
    if (p >= n) return;

    // hoist all 16 neighbor indices via shfl broadcast (R2 style)
    int jj = idx[p * KNN + sub];
    int jall[KNN];
    #pragma unroll
    for (int k = 0; k < KNN; ++k) jall[k] = __shfl(jj, k, 16);

    // issue all 16 bf16 gathers back-to-back (32 VGPRs of payload)
    uint2 vbuf[KNN];
    #pragma unroll
    for (int k = 0; k < KNN; ++k) vbuf[k] = xb[(size_t)jall[k] * 16 + sub];
    float4 own = xv[(size_t)p * 16 + sub];   // fp32 own row, in flight too
    float bb = b1[sub];
    float4 bq = ((const float4*)b2)[sub];

    float4 sum, mx;
    {
        float4 v = bf4_to_f4(vbuf[0]);
        sum = v; mx = v;
    }
    #pragma unroll
    for (int k = 1; k < KNN; ++k) {
        float4 v = bf4_to_f4(vbuf[k]);
        sum.x += v.x; sum.y += v.y; sum.z += v.z; sum.w += v.w;
        mx.x = fmaxf(mx.x, v.x); mx.y = fmaxf(mx.y, v.y);
        mx.z = fmaxf(mx.z, v.z); mx.w = fmaxf(mx.w, v.w);
    }
    const float inv_k = 1.0f / KNN;
    float4 mean = {sum.x * inv_k, sum.y * inv_k, sum.z * inv_k, sum.w * inv_k};

    // layer 1, mean path then max path (halves peak live-array pressure)
    float Hm, Hx;
    {
        float pm[HID];
        #pragma unroll
        for (int h = 0; h < HID; ++h) {
            float4 wv = w1q[h * 16 + sub];
            pm[h] = mean.x * wv.x + mean.y * wv.y + mean.z * wv.z + mean.w * wv.w;
        }
        Hm = fold16(pm, sub);
    }
    {
        float px[HID];
        #pragma unroll
        for (int h = 0; h < HID; ++h) {
            float4 wv = w1q[h * 16 + sub];
            px[h] = mx.x * wv.x + mx.y * wv.y + mx.z * wv.z + mx.w * wv.w;
        }
        Hx = fold16(px, sub);
    }
    float H = fmaxf(Hm + bb, 0.0f) + fmaxf(Hx + bb, 0.0f);

    // layer 2: out4[c] = sum_h H[h] * W2[h][c]
    float4 acc = {0.f, 0.f, 0.f, 0.f};
    #pragma unroll
    for (int h = 0; h < HID; ++h) {
        float Hh = __shfl(H, h, 16);
        float4 wv = w2q[h * 16 + sub];
        acc.x += Hh * wv.x; acc.y += Hh * wv.y; acc.z += Hh * wv.z; acc.w += Hh * wv.w;
    }
    float4 o;
    o.x = own.x * sigmoidf_(acc.x + 2.0f * bq.x);
    o.y = own.y * sigmoidf_(acc.y + 2.0f * bq.y);
    o.z = own.z * sigmoidf_(acc.z + 2.0f * bq.z);
    o.w = own.w * sigmoidf_(acc.w + 2.0f * bq.w);
    outse[(size_t)p * 16 + sub] = o;

    // per-row stats so phase B gathers 8B/neighbor instead of 256B
    float sm = o.x + o.y + o.z + o.w;
    float sx = fmaxf(fmaxf(o.x, o.y), fmaxf(o.z, o.w));
    #pragma unroll
    for (int m = 8; m >= 1; m >>= 1) {
        sm += __shfl_xor(sm, m);
        sx = fmaxf(sx, __shfl_xor(sx, m));
    }
    if (sub == 0) rowstat[p] = make_float2(sm * (1.0f / 64.0f), sx);
}

// Phase B: z[n] = (mean_k rowmean, max_k rowmax). 2 lanes per point (8 gathers
// each) -> 2x wave concurrency on this latency-bound gather.
__global__ __launch_bounds__(256) void kB(const int4* __restrict__ idxv,
        const float2* __restrict__ rowstat, float2* __restrict__ z, int n) {
    int t = blockIdx.x * 256 + threadIdx.x;
    int i = t >> 1, half = t & 1;
    if (i >= n) return;
    int4 a = idxv[(size_t)i * 4 + half * 2];
    int4 b = idxv[(size_t)i * 4 + half * 2 + 1];
    float2 s0 = rowstat[a.x], s1 = rowstat[a.y], s2 = rowstat[a.z], s3 = rowstat[a.w];
    float2 s4 = rowstat[b.x], s5 = rowstat[b.y], s6 = rowstat[b.z], s7 = rowstat[b.w];
    float zm = (s0.x + s1.x) + (s2.x + s3.x) + ((s4.x + s5.x) + (s6.x + s7.x));
    float zx = fmaxf(fmaxf(fmaxf(s0.y, s1.y), fmaxf(s2.y, s3.y)),
                     fmaxf(fmaxf(s4.y, s5.y), fmaxf(s6.y, s7.y)));
    zm += __shfl_xor(zm, 1);
    zx = fmaxf(zx, __shfl_xor(zx, 1));
    if (half == 0) z[i] = make_float2(zm * (1.0f / 16.0f), zx);
}

// Phase C (fused conv + scale): sig per point via LDS, then out = outse * sig
__global__ __launch_bounds__(256) void kC(const int* __restrict__ conv_idx,
        const float* __restrict__ conv_w, const float2* __restrict__ z,
        const float4* __restrict__ outse, float4* __restrict__ out, int n) {
    __shared__ float cw[54];
    __shared__ float sgate[256];
    if (threadIdx.x < 54) cw[threadIdx.x] = conv_w[threadIdx.x];
    __syncthreads();
    int base = blockIdx.x * 256;
    int i = base + threadIdx.x;
    if (i < n) {
        float acc = 0.0f;
        #pragma unroll
        for (int k = 0; k < 27; ++k) {
            int j = conv_idx[(size_t)i * 27 + k];   // branchless clamp + mask
            int jc = j >= 0 ? j : 0;
            float msk = j >= 0 ? 1.0f : 0.0f;
            float2 zz = z[jc];
            acc += msk * (zz.x * cw[2 * k] + zz.y * cw[2 * k + 1]);
        }
        sgate[threadIdx.x] = sigmoidf_(acc);
    }
    __syncthreads();
    int npts = n - base; if (npts > 256) npts = 256;
    int tot = npts * 16;                            // float4s this block owns
    for (int q = threadIdx.x; q < tot; q += 256) {
        float s = sgate[q >> 4];
        float4 v = outse[(size_t)base * 16 + q];
        out[(size_t)base * 16 + q] = make_float4(v.x * s, v.y * s, v.z * s, v.w * s);
    }
}

extern "C" void kernel_launch(void* const* d_in, const int* in_sizes, int n_in,
                              void* d_out, int out_size, void* d_ws, size_t ws_size,
                              hipStream_t stream) {
    const float* x_F    = (const float*)d_in[0];
    const float* W1     = (const float*)d_in[1];
    const float* b1     = (const float*)d_in[2];
    const float* W2     = (const float*)d_in[3];
    const float* b2     = (const float*)d_in[4];
    const float* conv_w = (const float*)d_in[5];
    const int*   idx    = (const int*)d_in[6];
    const int*   cidx   = (const int*)d_in[7];
    int n = in_sizes[0] / CH;   // 100000

    char* ws = (char*)d_ws;
    size_t off = 0;
    uint2*  xb      = (uint2*)(ws + off);  off += (size_t)n * CH * 2;   // bf16 table
    float*  outse   = (float*)(ws + off);  off += (size_t)n * CH * 4;
    float2* rowstat = (float2*)(ws + off); off += (size_t)n * 8;
    float2* zz      = (float2*)(ws + off); off += (size_t)n * 8;

    int n16 = n * 16;
    kX<<<(n16 + 255) / 256, 256, 0, stream>>>((const float4*)x_F, xb, n16);
    int blkA = (n + 15) / 16;
    kA<<<blkA, 256, 0, stream>>>((const float4*)x_F, xb, W1, b1, W2, b2, idx,
                                 (float4*)outse, rowstat, n);
    int blkB = (2 * n + 255) / 256;
    kB<<<blkB, 256, 0, stream>>>((const int4*)idx, rowstat, zz, n);
    int blkP = (n + 255) / 256;
    kC<<<blkP, 256, 0, stream>>>(cidx, conv_w, zz, (const float4*)outse,
                                 (float4*)d_out, n);
}

// Round 7
// 171.433 us; speedup vs baseline: 1.6709x; 1.4181x over previous
//
#include <hip/hip_runtime.h>
#include <math.h>

#define KNN 16
#define CH 64
#define HID 16
#define NEG_BIG (-3.402823466e+38f)

__device__ __forceinline__ float sigmoidf_(float x) {
    return 1.0f / (1.0f + __expf(-x));
}

// pack two fp32 into bf16x2 (RNE), a in low16, b in high16
__device__ __forceinline__ unsigned int pack_bf2(float a, float b) {
    unsigned int ua = __float_as_uint(a), ub = __float_as_uint(b);
    ua = (ua + 0x7FFFu + ((ua >> 16) & 1u)) >> 16;
    ub = (ub + 0x7FFFu + ((ub >> 16) & 1u)) & 0xFFFF0000u;
    return ua | ub;
}

// unpack 4 packed bf16 -> float4
__device__ __forceinline__ float4 bf4_to_f4(unsigned int lo, unsigned int hi) {
    float4 r;
    r.x = __uint_as_float(lo << 16);
    r.y = __uint_as_float(lo & 0xFFFF0000u);
    r.z = __uint_as_float(hi << 16);
    r.w = __uint_as_float(hi & 0xFFFF0000u);
    return r;
}

// paired fold-reduce across an 8-lane group: A[8],B[8] partials -> lane sub
// ends holding full sums A -> H[sub], B -> H[sub+8].
__device__ __forceinline__ void fold8_2(float A[8], float B[8], int sub) {
    #pragma unroll
    for (int m = 4; m >= 1; m >>= 1) {
        bool hi = (sub & m) != 0;
        #pragma unroll
        for (int i = 0; i < m; ++i) {
            float sA = hi ? A[i] : A[i + m], kA_ = hi ? A[i + m] : A[i];
            A[i] = kA_ + __shfl_xor(sA, m);
            float sB = hi ? B[i] : B[i + m], kB_ = hi ? B[i + m] : B[i];
            B[i] = kB_ + __shfl_xor(sB, m);
        }
    }
}

// Pre-pass: bf16 copy of x_F (halves gather lines + cache footprint for kA)
__global__ __launch_bounds__(256) void kX(const float4* __restrict__ xv,
                                          uint2* __restrict__ xb, int n16) {
    int i = blockIdx.x * 256 + threadIdx.x;
    if (i >= n16) return;
    float4 v = xv[i];
    uint2 r;
    r.x = pack_bf2(v.x, v.y);
    r.y = pack_bf2(v.z, v.w);
    xb[i] = r;
}

// Phase A: channel attention. 8 lanes per point (8 points/wave), lane owns 8
// channels (uint4 = 8 bf16, 16B). One bf16 row = 128B = one 8-lane slice ->
// gathers keep R2's proven dwordx4/1KB-per-inst shape at HALF the bytes and
// half the instructions. All 16 loads issued, then sched_barrier(0) pins the
// batch (R5's dwordx2+unpack codegen serialized issue -> 0.7 TB/s vs the
// ~2.0 TB/s L2-miss ceiling measured in R1/R2/R3). launch_bounds(256,3):
// room for the 64-VGPR load payload without spills.
__global__ __launch_bounds__(256, 3) void kA(const float4* __restrict__ xv,
        const uint4* __restrict__ xb4,
        const float* __restrict__ W1, const float* __restrict__ b1,
        const float* __restrict__ W2, const float* __restrict__ b2,
        const int2* __restrict__ idx2,
        float4* __restrict__ outse, float2* __restrict__ rowstat, int n) {
    __shared__ float4 w1a[128];   // w1a[h*8+s] = W1[(8s+0..3)][h]
    __shared__ float4 w1b[128];   // w1b[h*8+s] = W1[(8s+4..7)][h]
    __shared__ float4 w2q[256];   // float4 copy of W2 (16x64 row-major)
    int t = threadIdx.x;
    if (t < 128) {
        int h = t >> 3, s = t & 7;
        float4 a, b;
        a.x = W1[(8 * s + 0) * HID + h];
        a.y = W1[(8 * s + 1) * HID + h];
        a.z = W1[(8 * s + 2) * HID + h];
        a.w = W1[(8 * s + 3) * HID + h];
        b.x = W1[(8 * s + 4) * HID + h];
        b.y = W1[(8 * s + 5) * HID + h];
        b.z = W1[(8 * s + 6) * HID + h];
        b.w = W1[(8 * s + 7) * HID + h];
        w1a[t] = a;
        w1b[t] = b;
    }
    w2q[t] = ((const float4*)W2)[t];
    __syncthreads();

    int p = blockIdx.x * 32 + (t >> 3);
    int sub = t & 7;
    if (p >= n) return;

    // 16 neighbor indices live as int2 per lane; broadcast via width-8 shfl
    int2 jp = idx2[(size_t)p * 8 + sub];
    int jA[8], jB[8];
    #pragma unroll
    for (int s = 0; s < 8; ++s) {
        jA[s] = __shfl(jp.x, s, 8);
        jB[s] = __shfl(jp.y, s, 8);
    }

    // issue all 16 gathers + own-row/bias loads, then pin with sched_barrier
    uint4 va[8], vb[8];
    #pragma unroll
    for (int s = 0; s < 8; ++s) va[s] = xb4[(size_t)jA[s] * 8 + sub];
    #pragma unroll
    for (int s = 0; s < 8; ++s) vb[s] = xb4[(size_t)jB[s] * 8 + sub];
    float4 own0 = xv[(size_t)p * 16 + 2 * sub];
    float4 own1 = xv[(size_t)p * 16 + 2 * sub + 1];
    float b1a = b1[sub], b1b = b1[sub + 8];
    float4 bq0 = ((const float4*)b2)[2 * sub];
    float4 bq1 = ((const float4*)b2)[2 * sub + 1];
    __builtin_amdgcn_sched_barrier(0);

    float4 sumLo, sumHi, mxLo, mxHi;
    {
        float4 lo = bf4_to_f4(va[0].x, va[0].y);
        float4 hi = bf4_to_f4(va[0].z, va[0].w);
        sumLo = lo; mxLo = lo; sumHi = hi; mxHi = hi;
    }
    #pragma unroll
    for (int s = 1; s < 8; ++s) {
        float4 lo = bf4_to_f4(va[s].x, va[s].y);
        float4 hi = bf4_to_f4(va[s].z, va[s].w);
        sumLo.x += lo.x; sumLo.y += lo.y; sumLo.z += lo.z; sumLo.w += lo.w;
        sumHi.x += hi.x; sumHi.y += hi.y; sumHi.z += hi.z; sumHi.w += hi.w;
        mxLo.x = fmaxf(mxLo.x, lo.x); mxLo.y = fmaxf(mxLo.y, lo.y);
        mxLo.z = fmaxf(mxLo.z, lo.z); mxLo.w = fmaxf(mxLo.w, lo.w);
        mxHi.x = fmaxf(mxHi.x, hi.x); mxHi.y = fmaxf(mxHi.y, hi.y);
        mxHi.z = fmaxf(mxHi.z, hi.z); mxHi.w = fmaxf(mxHi.w, hi.w);
    }
    #pragma unroll
    for (int s = 0; s < 8; ++s) {
        float4 lo = bf4_to_f4(vb[s].x, vb[s].y);
        float4 hi = bf4_to_f4(vb[s].z, vb[s].w);
        sumLo.x += lo.x; sumLo.y += lo.y; sumLo.z += lo.z; sumLo.w += lo.w;
        sumHi.x += hi.x; sumHi.y += hi.y; sumHi.z += hi.z; sumHi.w += hi.w;
        mxLo.x = fmaxf(mxLo.x, lo.x); mxLo.y = fmaxf(mxLo.y, lo.y);
        mxLo.z = fmaxf(mxLo.z, lo.z); mxLo.w = fmaxf(mxLo.w, lo.w);
        mxHi.x = fmaxf(mxHi.x, hi.x); mxHi.y = fmaxf(mxHi.y, hi.y);
        mxHi.z = fmaxf(mxHi.z, hi.z); mxHi.w = fmaxf(mxHi.w, hi.w);
    }
    const float inv_k = 1.0f / KNN;
    float4 meLo = {sumLo.x * inv_k, sumLo.y * inv_k, sumLo.z * inv_k, sumLo.w * inv_k};
    float4 meHi = {sumHi.x * inv_k, sumHi.y * inv_k, sumHi.z * inv_k, sumHi.w * inv_k};

    // layer 1: mean path then max path; fold over the 8-lane group
    float Hm_a, Hm_b, Hx_a, Hx_b;
    {
        float A[8], B[8];
        #pragma unroll
        for (int h = 0; h < 8; ++h) {
            float4 wa = w1a[h * 8 + sub], wb = w1b[h * 8 + sub];
            A[h] = meLo.x * wa.x + meLo.y * wa.y + meLo.z * wa.z + meLo.w * wa.w
                 + meHi.x * wb.x + meHi.y * wb.y + meHi.z * wb.z + meHi.w * wb.w;
            float4 wa2 = w1a[(h + 8) * 8 + sub], wb2 = w1b[(h + 8) * 8 + sub];
            B[h] = meLo.x * wa2.x + meLo.y * wa2.y + meLo.z * wa2.z + meLo.w * wa2.w
                 + meHi.x * wb2.x + meHi.y * wb2.y + meHi.z * wb2.z + meHi.w * wb2.w;
        }
        fold8_2(A, B, sub);
        Hm_a = A[0]; Hm_b = B[0];
    }
    {
        float A[8], B[8];
        #pragma unroll
        for (int h = 0; h < 8; ++h) {
            float4 wa = w1a[h * 8 + sub], wb = w1b[h * 8 + sub];
            A[h] = mxLo.x * wa.x + mxLo.y * wa.y + mxLo.z * wa.z + mxLo.w * wa.w
                 + mxHi.x * wb.x + mxHi.y * wb.y + mxHi.z * wb.z + mxHi.w * wb.w;
            float4 wa2 = w1a[(h + 8) * 8 + sub], wb2 = w1b[(h + 8) * 8 + sub];
            B[h] = mxLo.x * wa2.x + mxLo.y * wa2.y + mxLo.z * wa2.z + mxLo.w * wa2.w
                 + mxHi.x * wb2.x + mxHi.y * wb2.y + mxHi.z * wb2.z + mxHi.w * wb2.w;
        }
        fold8_2(A, B, sub);
        Hx_a = A[0]; Hx_b = B[0];
    }
    float H_a = fmaxf(Hm_a + b1a, 0.0f) + fmaxf(Hx_a + b1a, 0.0f);
    float H_b = fmaxf(Hm_b + b1b, 0.0f) + fmaxf(Hx_b + b1b, 0.0f);

    // layer 2: own 8 channels = sum_h H[h] * W2[h][c]
    float4 a0 = {0.f, 0.f, 0.f, 0.f}, a1 = {0.f, 0.f, 0.f, 0.f};
    #pragma unroll
    for (int h = 0; h < 8; ++h) {
        float Hh = __shfl(H_a, h, 8);
        float4 w0 = w2q[h * 16 + 2 * sub], w1v = w2q[h * 16 + 2 * sub + 1];
        a0.x += Hh * w0.x; a0.y += Hh * w0.y; a0.z += Hh * w0.z; a0.w += Hh * w0.w;
        a1.x += Hh * w1v.x; a1.y += Hh * w1v.y; a1.z += Hh * w1v.z; a1.w += Hh * w1v.w;
    }
    #pragma unroll
    for (int h = 0; h < 8; ++h) {
        float Hh = __shfl(H_b, h, 8);
        float4 w0 = w2q[(h + 8) * 16 + 2 * sub], w1v = w2q[(h + 8) * 16 + 2 * sub + 1];
        a0.x += Hh * w0.x; a0.y += Hh * w0.y; a0.z += Hh * w0.z; a0.w += Hh * w0.w;
        a1.x += Hh * w1v.x; a1.y += Hh * w1v.y; a1.z += Hh * w1v.z; a1.w += Hh * w1v.w;
    }
    float4 o0, o1;
    o0.x = own0.x * sigmoidf_(a0.x + 2.0f * bq0.x);
    o0.y = own0.y * sigmoidf_(a0.y + 2.0f * bq0.y);
    o0.z = own0.z * sigmoidf_(a0.z + 2.0f * bq0.z);
    o0.w = own0.w * sigmoidf_(a0.w + 2.0f * bq0.w);
    o1.x = own1.x * sigmoidf_(a1.x + 2.0f * bq1.x);
    o1.y = own1.y * sigmoidf_(a1.y + 2.0f * bq1.y);
    o1.z = own1.z * sigmoidf_(a1.z + 2.0f * bq1.z);
    o1.w = own1.w * sigmoidf_(a1.w + 2.0f * bq1.w);
    outse[(size_t)p * 16 + 2 * sub] = o0;
    outse[(size_t)p * 16 + 2 * sub + 1] = o1;

    // per-row stats for phase B (8B/neighbor there instead of 128B)
    float sm = (o0.x + o0.y + o0.z + o0.w) + (o1.x + o1.y + o1.z + o1.w);
    float sx = fmaxf(fmaxf(fmaxf(o0.x, o0.y), fmaxf(o0.z, o0.w)),
                     fmaxf(fmaxf(o1.x, o1.y), fmaxf(o1.z, o1.w)));
    #pragma unroll
    for (int m = 4; m >= 1; m >>= 1) {
        sm += __shfl_xor(sm, m);
        sx = fmaxf(sx, __shfl_xor(sx, m));
    }
    if (sub == 0) rowstat[p] = make_float2(sm * (1.0f / 64.0f), sx);
}

// Phase B: z[n] = (mean_k rowmean, max_k rowmax). 2 lanes per point.
__global__ __launch_bounds__(256) void kB(const int4* __restrict__ idxv,
        const float2* __restrict__ rowstat, float2* __restrict__ z, int n) {
    int t = blockIdx.x * 256 + threadIdx.x;
    int i = t >> 1, half = t & 1;
    if (i >= n) return;
    int4 a = idxv[(size_t)i * 4 + half * 2];
    int4 b = idxv[(size_t)i * 4 + half * 2 + 1];
    float2 s0 = rowstat[a.x], s1 = rowstat[a.y], s2 = rowstat[a.z], s3 = rowstat[a.w];
    float2 s4 = rowstat[b.x], s5 = rowstat[b.y], s6 = rowstat[b.z], s7 = rowstat[b.w];
    float zm = (s0.x + s1.x) + (s2.x + s3.x) + ((s4.x + s5.x) + (s6.x + s7.x));
    float zx = fmaxf(fmaxf(fmaxf(s0.y, s1.y), fmaxf(s2.y, s3.y)),
                     fmaxf(fmaxf(s4.y, s5.y), fmaxf(s6.y, s7.y)));
    zm += __shfl_xor(zm, 1);
    zx = fmaxf(zx, __shfl_xor(zx, 1));
    if (half == 0) z[i] = make_float2(zm * (1.0f / 16.0f), zx);
}

// Phase C (fused conv + scale): sig per point via LDS, then out = outse * sig
__global__ __launch_bounds__(256) void kC(const int* __restrict__ conv_idx,
        const float* __restrict__ conv_w, const float2* __restrict__ z,
        const float4* __restrict__ outse, float4* __restrict__ out, int n) {
    __shared__ float cw[54];
    __shared__ float sgate[256];
    if (threadIdx.x < 54) cw[threadIdx.x] = conv_w[threadIdx.x];
    __syncthreads();
    int base = blockIdx.x * 256;
    int i = base + threadIdx.x;
    if (i < n) {
        float acc = 0.0f;
        #pragma unroll
        for (int k = 0; k < 27; ++k) {
            int j = conv_idx[(size_t)i * 27 + k];   // branchless clamp + mask
            int jc = j >= 0 ? j : 0;
            float msk = j >= 0 ? 1.0f : 0.0f;
            float2 zz = z[jc];
            acc += msk * (zz.x * cw[2 * k] + zz.y * cw[2 * k + 1]);
        }
        sgate[threadIdx.x] = sigmoidf_(acc);
    }
    __syncthreads();
    int npts = n - base; if (npts > 256) npts = 256;
    int tot = npts * 16;                            // float4s this block owns
    for (int q = threadIdx.x; q < tot; q += 256) {
        float s = sgate[q >> 4];
        float4 v = outse[(size_t)base * 16 + q];
        out[(size_t)base * 16 + q] = make_float4(v.x * s, v.y * s, v.z * s, v.w * s);
    }
}

extern "C" void kernel_launch(void* const* d_in, const int* in_sizes, int n_in,
                              void* d_out, int out_size, void* d_ws, size_t ws_size,
                              hipStream_t stream) {
    const float* x_F    = (const float*)d_in[0];
    const float* W1     = (const float*)d_in[1];
    const float* b1     = (const float*)d_in[2];
    const float* W2     = (const float*)d_in[3];
    const float* b2     = (const float*)d_in[4];
    const float* conv_w = (const float*)d_in[5];
    const int*   idx    = (const int*)d_in[6];
    const int*   cidx   = (const int*)d_in[7];
    int n = in_sizes[0] / CH;   // 100000

    char* ws = (char*)d_ws;
    size_t off = 0;
    uint2*  xb      = (uint2*)(ws + off);  off += (size_t)n * CH * 2;   // bf16 table
    float*  outse   = (float*)(ws + off);  off += (size_t)n * CH * 4;
    float2* rowstat = (float2*)(ws + off); off += (size_t)n * 8;
    float2* zz      = (float2*)(ws + off); off += (size_t)n * 8;

    int n16 = n * 16;
    kX<<<(n16 + 255) / 256, 256, 0, stream>>>((const float4*)x_F, xb, n16);
    int blkA = (n + 31) / 32;
    kA<<<blkA, 256, 0, stream>>>((const float4*)x_F, (const uint4*)xb,
                                 W1, b1, W2, b2, (const int2*)idx,
                                 (float4*)outse, rowstat, n);
    int blkB = (2 * n + 255) / 256;
    kB<<<blkB, 256, 0, stream>>>((const int4*)idx, rowstat, zz, n);
    int blkP = (n + 255) / 256;
    kC<<<blkP, 256, 0, stream>>>(cidx, conv_w, zz, (const float4*)outse,
                                 (float4*)d_out, n);
}